// Round 1
// 550.955 us; speedup vs baseline: 1.1842x; 1.1842x over previous
//
#include <hip/hip_runtime.h>
#include <math.h>

#define T_FRAMES 24000
#define NC1 97
#define NC2 300
#define NCC 397          // NC1 + NC2
#define NA 3806
#define NA_PAD 3808      // padded to int4 multiple
#define H_DIM 909        // 512 + 97 + 300
#define COFF 512         // offset of clogit within feature row
#define SLG_STRIDE 400   // padded row stride for seg_lg (16B aligned)

// ---------------- wave-level reduction helpers (no barriers) ----------------

__device__ __forceinline__ float waveMax(float v) {
#pragma unroll
    for (int off = 32; off > 0; off >>= 1) v = fmaxf(v, __shfl_xor(v, off));
    return v;
}

__device__ __forceinline__ float waveSum(float v) {
#pragma unroll
    for (int off = 32; off > 0; off >>= 1) v += __shfl_xor(v, off);
    return v;
}

// monotone float -> u32 mapping (preserves <) for packed argmax keys
__device__ __forceinline__ unsigned flip32(float f) {
    unsigned u = __float_as_uint(f);
    return (u & 0x80000000u) ? ~u : (u | 0x80000000u);
}

// ---------------- kernel 0: pack (vid,nid) into one int ---------------------

__global__ __launch_bounds__(256) void k_pack(const int* __restrict__ vids,
                                              const int* __restrict__ nids,
                                              int* __restrict__ pk) {
    int a = blockIdx.x * 256 + threadIdx.x;
    if (a < NA_PAD) pk[a] = (a < NA) ? (vids[a] | (nids[a] << 16)) : 0;
}

// ---------------- kernel 1: per-frame stats + argmax ------------------------
// one WAVE per frame (4 frames/block). No __syncthreads anywhere.
// argmax is shift-invariant wrt log-softmax constants -> run it on RAW logits.

__global__ __launch_bounds__(256) void k_frame(const float* __restrict__ ff,
                                               const int* __restrict__ pk,
                                               float2* __restrict__ fstats,
                                               int* __restrict__ pred) {
    const int tid = threadIdx.x;
    const int wid = tid >> 6, lane = tid & 63;
    const int t = blockIdx.x * 4 + wid;

    __shared__ float sh[4][SLG_STRIDE];
    float* S = sh[wid];                       // this wave's private slice

    const float* row = ff + (size_t)t * H_DIM + COFF;

    float xv[7];
    float vmax = -INFINITY, nmax = -INFINITY;
#pragma unroll
    for (int j = 0; j < 7; j++) {
        const int idx = lane + j * 64;
        float x = -INFINITY;
        if (idx < NCC) { x = row[idx]; S[idx] = x; }
        xv[j] = x;
        if (idx < NC1) vmax = fmaxf(vmax, x);
        else           nmax = fmaxf(nmax, x);   // idx >= NCC contributes -inf
    }
    vmax = waveMax(vmax);
    nmax = waveMax(nmax);

    float vs = 0.f, ns = 0.f;
#pragma unroll
    for (int j = 0; j < 7; j++) {
        const int idx = lane + j * 64;
        if (idx < NC1)      vs += __expf(xv[j] - vmax);
        else if (idx < NCC) ns += __expf(xv[j] - nmax);
    }
    vs = waveSum(vs);
    ns = waveSum(ns);
    const float c1 = vmax + __logf(vs);       // mV + lseV
    const float c2 = nmax + __logf(ns);       // mN + lseN

    // argmax over raw sums, packed-key wave reduce.
    // key = flip(val)<<32 | ~a : max key => max val, tie => lowest action idx.
    const int4* pk4 = (const int4*)pk;
    unsigned long long best = 0ull;
    for (int g = lane; g < NA_PAD / 4; g += 64) {
        const int4 p4 = pk4[g];
        const int pv[4] = {p4.x, p4.y, p4.z, p4.w};
#pragma unroll
        for (int j = 0; j < 4; j++) {
            const int a = g * 4 + j;
            if (a < NA) {
                const int p = pv[j];
                const float val = S[p & 0xffff] + S[NC1 + (p >> 16)];
                const unsigned long long key =
                    ((unsigned long long)flip32(val) << 32) | (unsigned)(~(unsigned)a);
                best = (key > best) ? key : best;
            }
        }
    }
#pragma unroll
    for (int off = 32; off > 0; off >>= 1) {
        unsigned long long o = __shfl_xor(best, off);
        best = (o > best) ? o : best;
    }

    if (lane == 0) {
        pred[t] = (int)(~(unsigned)best);
        fstats[t] = make_float2(c1, c2);
    }
}

// ---------------- kernel 2: single-block scan -> seg_id, seg_start, S -------
// coalesced global access via LDS u16 staging (48 KB).

__global__ __launch_bounds__(1024) void k_scan(const int* __restrict__ pred,
                                               int* __restrict__ seg_id,
                                               int* __restrict__ seg_start,
                                               int* __restrict__ Scount) {
    const int tid = threadIdx.x;
    __shared__ unsigned short sid16[T_FRAMES];   // flags, then seg ids (S<=24000<65536)
    __shared__ int wsum[16];

    // phase A: change flags, coalesced reads
    for (int t = tid; t < T_FRAMES; t += 1024) {
        int chg = (t > 0) ? (pred[t] != pred[t - 1]) : 0;
        sid16[t] = (unsigned short)chg;
    }
    __syncthreads();

    // phase B: per-chunk counts + block scan + in-place id conversion
    const int CH = (T_FRAMES + 1023) / 1024;  // 24
    const int base = tid * CH;
    int cnt = 0;
    for (int k = 0; k < CH; k++) {
        int t = base + k;
        if (t < T_FRAMES) cnt += sid16[t];
    }
    const int lane = tid & 63, wid = tid >> 6;
    int inc = cnt;
#pragma unroll
    for (int d = 1; d < 64; d <<= 1) {
        int n = __shfl_up(inc, d);
        if (lane >= d) inc += n;
    }
    if (lane == 63) wsum[wid] = inc;
    __syncthreads();
    if (tid == 0) {
        int acc = 0;
        for (int i = 0; i < 16; i++) { int x = wsum[i]; wsum[i] = acc; acc += x; }
    }
    __syncthreads();
    int sid = wsum[wid] + inc - cnt;   // segment id at chunk start

    for (int k = 0; k < CH; k++) {
        int t = base + k;
        if (t >= T_FRAMES) break;
        if (t == 0) {
            seg_start[0] = 0;
        } else if (sid16[t]) {
            sid++;
            seg_start[sid] = t;
        }
        sid16[t] = (unsigned short)sid;
        if (t == T_FRAMES - 1) *Scount = sid + 1;
    }
    __syncthreads();

    // phase C: coalesced write-out
    for (int t = tid; t < T_FRAMES; t += 1024) seg_id[t] = (int)sid16[t];
}

// ---------------- kernel 3: per-segment mean + log-softmax table ------------
// one WAVE per (potential) segment; register accumulators, no LDS, no barriers.

__global__ __launch_bounds__(256) void k_seg(const float* __restrict__ ff,
                                             const int* __restrict__ seg_start,
                                             const int* __restrict__ Scount,
                                             float* __restrict__ seg_lg) {
    const int tid = threadIdx.x;
    const int wid = tid >> 6, lane = tid & 63;
    const int s = blockIdx.x * 4 + wid;
    const int S = *Scount;
    if (s >= S) return;

    const int start = seg_start[s];
    const int end = (s + 1 < S) ? seg_start[s + 1] : T_FRAMES;
    const int len = end - start;

    float acc[7] = {0.f, 0.f, 0.f, 0.f, 0.f, 0.f, 0.f};
    const float* basep = ff + (size_t)start * H_DIM + COFF;
    for (int k = 0; k < len; k++) {
        const float* p = basep + (size_t)k * H_DIM;
#pragma unroll
        for (int j = 0; j < 7; j++) {
            const int idx = lane + j * 64;
            if (idx < NCC) acc[j] += p[idx];
        }
    }
    const float inv = 1.f / (float)len;

    float xv[7];
    float vmax = -INFINITY, nmax = -INFINITY;
#pragma unroll
    for (int j = 0; j < 7; j++) {
        const int idx = lane + j * 64;
        float x = (idx < NCC) ? acc[j] * inv : -INFINITY;
        xv[j] = x;
        if (idx < NC1) vmax = fmaxf(vmax, x);
        else           nmax = fmaxf(nmax, x);
    }
    vmax = waveMax(vmax);
    nmax = waveMax(nmax);

    float vs = 0.f, ns = 0.f;
#pragma unroll
    for (int j = 0; j < 7; j++) {
        const int idx = lane + j * 64;
        if (idx < NC1)      vs += __expf(xv[j] - vmax);
        else if (idx < NCC) ns += __expf(xv[j] - nmax);
    }
    vs = waveSum(vs);
    ns = waveSum(ns);
    const float lv = __logf(vs), ln_ = __logf(ns);

    float* dst = seg_lg + (size_t)s * SLG_STRIDE;
#pragma unroll
    for (int j = 0; j < 7; j++) {
        const int idx = lane + j * 64;
        if (idx < NCC)
            dst[idx] = (idx < NC1) ? ((xv[j] - vmax) - lv) : ((xv[j] - nmax) - ln_);
    }
}

// ---------------- kernel 4: fused output write ------------------------------
// one WAVE per frame; combined frame+segment table => 2 LDS gathers/action
// (was 4); float2 packed stores (3806 = 2*1903 exactly, rows 8B-aligned).

__global__ __launch_bounds__(256) void k_out(const float* __restrict__ ff,
                                             const int* __restrict__ pk,
                                             const float2* __restrict__ fstats,
                                             const int* __restrict__ seg_id,
                                             const float* __restrict__ seg_lg,
                                             float* __restrict__ out) {
    const int tid = threadIdx.x;
    const int wid = tid >> 6, lane = tid & 63;
    const int t = blockIdx.x * 4 + wid;

    __shared__ float sh[4][SLG_STRIDE];
    float* S = sh[wid];

    const int s = seg_id[t];
    const float2 c = fstats[t];
    const float* row = ff + (size_t)t * H_DIM + COFF;
    const float* srow = seg_lg + (size_t)s * SLG_STRIDE;

    // combined table: S[i] = (row[i]-c) + slg[i]  (frame logprob + seg logprob)
#pragma unroll
    for (int j = 0; j < 7; j++) {
        const int idx = lane + j * 64;
        if (idx < NCC)
            S[idx] = row[idx] + srow[idx] - ((idx < NC1) ? c.x : c.y);
    }

    const int2* pk2 = (const int2*)pk;
    float* orow = out + (size_t)t * NA;
    for (int g = lane; g < NA / 2; g += 64) {
        const int2 p2 = pk2[g];
        float2 o;
        o.x = S[p2.x & 0xffff] + S[NC1 + (p2.x >> 16)];
        o.y = S[p2.y & 0xffff] + S[NC1 + (p2.y >> 16)];
        *(float2*)(orow + 2 * g) = o;
    }
}

// ---------------- launcher --------------------------------------------------

extern "C" void kernel_launch(void* const* d_in, const int* in_sizes, int n_in,
                              void* d_out, int out_size, void* d_ws, size_t ws_size,
                              hipStream_t stream) {
    const float* ff = (const float*)d_in[0];
    const int* vids = (const int*)d_in[1];
    const int* nids = (const int*)d_in[2];
    float* out = (float*)d_out;

    char* ws = (char*)d_ws;
    size_t off = 0;
    float2* fstats = (float2*)(ws + off); off += (size_t)T_FRAMES * 8;          // 192000
    int* pred = (int*)(ws + off);         off += (size_t)T_FRAMES * 4;          // 96000
    int* seg_id = (int*)(ws + off);       off += (size_t)T_FRAMES * 4;          // 96000
    int* seg_start = (int*)(ws + off);    off += (size_t)T_FRAMES * 4;          // 96000
    int* Scount = (int*)(ws + off);       off += 16;
    int* pk = (int*)(ws + off);           off += (size_t)NA_PAD * 4;            // 15232
    float* seg_lg = (float*)(ws + off);   off += (size_t)T_FRAMES * SLG_STRIDE * 4; // 38.4 MB

    k_pack<<<(NA_PAD + 255) / 256, 256, 0, stream>>>(vids, nids, pk);
    k_frame<<<T_FRAMES / 4, 256, 0, stream>>>(ff, pk, fstats, pred);
    k_scan<<<1, 1024, 0, stream>>>(pred, seg_id, seg_start, Scount);
    k_seg<<<T_FRAMES / 4, 256, 0, stream>>>(ff, seg_start, Scount, seg_lg);
    k_out<<<T_FRAMES / 4, 256, 0, stream>>>(ff, pk, fstats, seg_id, seg_lg, out);
}

// Round 3
// 521.340 us; speedup vs baseline: 1.2515x; 1.0568x over previous
//
#include <hip/hip_runtime.h>
#include <math.h>

#define T_FRAMES 24000
#define NC1 97
#define NC2 300
#define NCC 397          // NC1 + NC2
#define NA 3806
#define NA_PAD 3808
#define NSORT 4096       // padded key-list length (uint4 multiple)
#define H_DIM 909        // 512 + 97 + 300
#define COFF 512         // offset of clogit within feature row
#define TAB 400          // padded LDS table stride

// ---------------- wave-level reduction helpers (no barriers) ----------------

__device__ __forceinline__ float waveMax(float v) {
#pragma unroll
    for (int off = 32; off > 0; off >>= 1) v = fmaxf(v, __shfl_xor(v, off));
    return v;
}

__device__ __forceinline__ float waveSum(float v) {
#pragma unroll
    for (int off = 32; off > 0; off >>= 1) v += __shfl_xor(v, off);
    return v;
}

// monotone float -> u32 mapping (preserves <) for packed argmax keys
__device__ __forceinline__ unsigned flip32(float f) {
    unsigned u = __float_as_uint(f);
    return (u & 0x80000000u) ? ~u : (u | 0x80000000u);
}

// ---------------- kernel 0: prep — pack pk + nid-bucketed key list ----------
// single block. counting-sort actions by nid (unstable; argmax reduce is
// order-independent). key = nid<<19 | vid<<12 | a  (9+7+12 bits = 28).

__global__ __launch_bounds__(256) void k_prep(const int* __restrict__ vids,
                                              const int* __restrict__ nids,
                                              int* __restrict__ pk,
                                              unsigned* __restrict__ skey) {
    __shared__ unsigned cnt[NC2];
    __shared__ unsigned ofs[NC2];
    const int tid = threadIdx.x;

    for (int i = tid; i < NC2; i += 256) cnt[i] = 0u;
    __syncthreads();

    for (int a = tid; a < NA; a += 256) {
        int v = vids[a], n = nids[a];
        pk[a] = v | (n << 16);
        atomicAdd(&cnt[n], 1u);
    }
    __syncthreads();

    // exclusive scan of 300 bucket counts (wave 0, shfl scan, 5 chunks of 64)
    if (tid < 64) {
        unsigned run = 0;
        for (int c = 0; c < 5; c++) {
            int i = c * 64 + tid;
            unsigned x = (i < NC2) ? cnt[i] : 0u;
            unsigned inc = x;
#pragma unroll
            for (int d = 1; d < 64; d <<= 1) {
                unsigned y = __shfl_up(inc, d);
                if (tid >= d) inc += y;
            }
            if (i < NC2) ofs[i] = run + inc - x;
            run += __shfl(inc, 63);
        }
    }
    __syncthreads();

    for (int a = tid; a < NA; a += 256) {
        unsigned v = (unsigned)vids[a], n = (unsigned)nids[a];
        unsigned p = atomicAdd(&ofs[n], 1u);
        skey[p] = (n << 19) | (v << 12) | (unsigned)a;
    }
    for (int i = NA + tid; i < NSORT; i += 256) skey[i] = 0xFFFFFFFFu;
}

// ---------------- kernel 1: per-frame stats + argmax ------------------------
// one WAVE per frame. argmax walks the nid-bucketed key list so the 300-slot
// nid gather is broadcast-friendly (was the dominant LDS bank-conflict cost).

__global__ __launch_bounds__(256) void k_frame(const float* __restrict__ ff,
                                               const unsigned* __restrict__ skey,
                                               float2* __restrict__ fstats,
                                               int* __restrict__ pred) {
    const int tid = threadIdx.x;
    const int wid = tid >> 6, lane = tid & 63;
    const int t = blockIdx.x * 4 + wid;

    __shared__ float sh[4][TAB];
    float* S = sh[wid];

    const float* row = ff + (size_t)t * H_DIM + COFF;

    float xv[7];
    float vmax = -INFINITY, nmax = -INFINITY;
#pragma unroll
    for (int j = 0; j < 7; j++) {
        const int idx = lane + j * 64;
        float x = -INFINITY;
        if (idx < NCC) { x = row[idx]; S[idx] = x; }
        xv[j] = x;
        if (idx < NC1) vmax = fmaxf(vmax, x);
        else           nmax = fmaxf(nmax, x);
    }
    vmax = waveMax(vmax);
    nmax = waveMax(nmax);

    float vs = 0.f, ns = 0.f;
#pragma unroll
    for (int j = 0; j < 7; j++) {
        const int idx = lane + j * 64;
        if (idx < NC1)      vs += __expf(xv[j] - vmax);
        else if (idx < NCC) ns += __expf(xv[j] - nmax);
    }
    vs = waveSum(vs);
    ns = waveSum(ns);
    const float c1 = vmax + __logf(vs);       // mV + lseV
    const float c2 = nmax + __logf(ns);       // mN + lseN

    // argmax over raw sums (shift-invariant). packed key:
    // flip(val)<<32 | (~a & 0xFFF) -> max val, tie -> lowest action idx.
    const uint4* sk4 = (const uint4*)skey;
    unsigned long long best = 0ull;
    for (int g = lane; g < NSORT / 4; g += 64) {      // 16 iterations
        const uint4 kq = sk4[g];
        const unsigned ks[4] = {kq.x, kq.y, kq.z, kq.w};
#pragma unroll
        for (int j = 0; j < 4; j++) {
            const unsigned kk = ks[j];
            if (kk != 0xFFFFFFFFu) {
                const float val = S[(kk >> 12) & 0x7Fu] + S[NC1 + (kk >> 19)];
                const unsigned long long rk =
                    ((unsigned long long)flip32(val) << 32) | ((~kk) & 0xFFFu);
                best = (rk > best) ? rk : best;
            }
        }
    }
#pragma unroll
    for (int off = 32; off > 0; off >>= 1) {
        unsigned long long o = __shfl_xor(best, off);
        best = (o > best) ? o : best;
    }

    if (lane == 0) {
        pred[t] = (int)((~(unsigned)best) & 0xFFFu);
        fstats[t] = make_float2(c1, c2);
    }
}

// ---------------- kernel 2: single-block scan -> seg_start, Scount ----------

__global__ __launch_bounds__(1024) void k_scan(const int* __restrict__ pred,
                                               int* __restrict__ seg_start,
                                               int* __restrict__ Scount) {
    const int tid = threadIdx.x;
    __shared__ unsigned short flg[T_FRAMES];
    __shared__ int wsum[16];

    for (int t = tid; t < T_FRAMES; t += 1024)
        flg[t] = (unsigned short)((t > 0) ? (pred[t] != pred[t - 1]) : 0);
    __syncthreads();

    const int CH = (T_FRAMES + 1023) / 1024;  // 24
    const int base = tid * CH;
    int cnt = 0;
    for (int k = 0; k < CH; k++) {
        int t = base + k;
        if (t < T_FRAMES) cnt += flg[t];
    }
    const int lane = tid & 63, wid = tid >> 6;
    int inc = cnt;
#pragma unroll
    for (int d = 1; d < 64; d <<= 1) {
        int n = __shfl_up(inc, d);
        if (lane >= d) inc += n;
    }
    if (lane == 63) wsum[wid] = inc;
    __syncthreads();
    if (tid == 0) {
        int acc = 0;
        for (int i = 0; i < 16; i++) { int x = wsum[i]; wsum[i] = acc; acc += x; }
    }
    __syncthreads();
    int sid = wsum[wid] + inc - cnt;

    for (int k = 0; k < CH; k++) {
        int t = base + k;
        if (t >= T_FRAMES) break;
        if (t == 0) seg_start[0] = 0;
        else if (flg[t]) { sid++; seg_start[sid] = t; }
        if (t == T_FRAMES - 1) *Scount = sid + 1;
    }
}

// ---------------- kernel 3: fused segment softmax + output ------------------
// one WAVE per segment: mean + log-softmax in registers, then for each frame
// of the segment build the combined table in LDS and gather-write the output
// row. eliminates the 76 MB seg_lg round-trip and the separate k_out launch.

__global__ __launch_bounds__(256) void k_segout(const float* __restrict__ ff,
                                                const int* __restrict__ pk,
                                                const float2* __restrict__ fstats,
                                                const int* __restrict__ seg_start,
                                                const int* __restrict__ Scount,
                                                float* __restrict__ out) {
    const int tid = threadIdx.x;
    const int wid = tid >> 6, lane = tid & 63;
    const int s = blockIdx.x * 4 + wid;
    const int S = *Scount;
    if (s >= S) return;

    const int start = seg_start[s];
    int end = (s + 1 < S) ? seg_start[s + 1] : T_FRAMES;
    if (end > T_FRAMES) end = T_FRAMES;
    const int len = end - start;

    // segment mean of clogit columns
    float acc[7] = {0.f, 0.f, 0.f, 0.f, 0.f, 0.f, 0.f};
    const float* basep = ff + (size_t)start * H_DIM + COFF;
    for (int k = 0; k < len; k++) {
        const float* p = basep + (size_t)k * H_DIM;
#pragma unroll
        for (int j = 0; j < 7; j++) {
            const int idx = lane + j * 64;
            if (idx < NCC) acc[j] += p[idx];
        }
    }
    const float inv = 1.f / (float)len;

    // log-softmax of the mean (seg log-probs, kept in registers)
    float lp[7];
    float vmax = -INFINITY, nmax = -INFINITY;
#pragma unroll
    for (int j = 0; j < 7; j++) {
        const int idx = lane + j * 64;
        float x = (idx < NCC) ? acc[j] * inv : -INFINITY;
        lp[j] = x;
        if (idx < NC1) vmax = fmaxf(vmax, x);
        else           nmax = fmaxf(nmax, x);
    }
    vmax = waveMax(vmax);
    nmax = waveMax(nmax);
    float vs = 0.f, ns = 0.f;
#pragma unroll
    for (int j = 0; j < 7; j++) {
        const int idx = lane + j * 64;
        if (idx < NC1)      vs += __expf(lp[j] - vmax);
        else if (idx < NCC) ns += __expf(lp[j] - nmax);
    }
    vs = waveSum(vs);
    ns = waveSum(ns);
    const float cv = vmax + __logf(vs);
    const float cn = nmax + __logf(ns);
#pragma unroll
    for (int j = 0; j < 7; j++) {
        const int idx = lane + j * 64;
        lp[j] -= (idx < NC1) ? cv : cn;
    }

    __shared__ float sh[4][TAB];
    float* Stab = sh[wid];
    const int2* pk2 = (const int2*)pk;

    for (int t = start; t < end; t++) {
        const float2 c = fstats[t];
        const float* row = ff + (size_t)t * H_DIM + COFF;
        // combined table: frame logprob + seg logprob
#pragma unroll
        for (int j = 0; j < 7; j++) {
            const int idx = lane + j * 64;
            if (idx < NCC)
                Stab[idx] = row[idx] + lp[j] - ((idx < NC1) ? c.x : c.y);
        }
        // same-wave LDS ops complete in order: no barrier needed
        float* orow = out + (size_t)t * NA;
        for (int g = lane; g < NA / 2; g += 64) {
            const int2 p2 = pk2[g];
            float2 o;
            o.x = Stab[p2.x & 0xffff] + Stab[NC1 + (p2.x >> 16)];
            o.y = Stab[p2.y & 0xffff] + Stab[NC1 + (p2.y >> 16)];
            *(float2*)(orow + 2 * g) = o;
        }
    }
}

// ---------------- launcher --------------------------------------------------

extern "C" void kernel_launch(void* const* d_in, const int* in_sizes, int n_in,
                              void* d_out, int out_size, void* d_ws, size_t ws_size,
                              hipStream_t stream) {
    const float* ff = (const float*)d_in[0];
    const int* vids = (const int*)d_in[1];
    const int* nids = (const int*)d_in[2];
    float* out = (float*)d_out;

    char* ws = (char*)d_ws;
    size_t off = 0;
    float2* fstats = (float2*)(ws + off);  off += (size_t)T_FRAMES * 8;
    int* pred = (int*)(ws + off);          off += (size_t)T_FRAMES * 4;
    int* seg_start = (int*)(ws + off);     off += (size_t)T_FRAMES * 4;
    int* Scount = (int*)(ws + off);        off += 16;
    int* pk = (int*)(ws + off);            off += (size_t)NA_PAD * 4;
    unsigned* skey = (unsigned*)(ws + off); off += (size_t)NSORT * 4;

    k_prep<<<1, 256, 0, stream>>>(vids, nids, pk, skey);
    k_frame<<<T_FRAMES / 4, 256, 0, stream>>>(ff, skey, fstats, pred);
    k_scan<<<1, 1024, 0, stream>>>(pred, seg_start, Scount);
    k_segout<<<T_FRAMES / 4, 256, 0, stream>>>(ff, pk, fstats, seg_start, Scount, out);
}